// Round 21
// baseline (372.389 us; speedup 1.0000x reference)
//
#include <hip/hip_runtime.h>

// EntityLinker fused edge-MLP for MI355X (gfx950).
// Round 33: attack the 50us outside fused_mlp (launch/prep tail).
//   R32 measured: 287.0us dispatch (VALU trim exhausted: -8% VALUBusy ->
//   -1% dur). Interior is latency-structural, no pipe >35%. But bench
//   dur_us (the scored metric) is consistently ~50-60us above the
//   fused_mlp dispatch (R24 381/327, R31 349/290, R32 337/287): prep
//   kernels + extra launch slots. Fix:
//   1) Drop prep_node: gather f32 node rows directly in Phase A, convert
//      bf16 in-register via v_cvt_pk_bf16_f32 (RNE == f2bf's RNE ->
//      bit-identical LDS contents). Gather bytes 2x (FETCH ~94->~190MB,
//      <9% HBM peak). -1 kernel, -1 launch, -38MB of prep traffic.
//   2) Merge prep_w1+prep_w2 (grid 640, branch on blockIdx). -1 launch.
//   fused_mlp interior byte-identical to R32 (best measured).
//   Predict: bench 337 -> 312-325; dispatch 287 -> 288-296; FETCH ~190MB.
//   Flat bench + flat dispatch => gap is harness fixed cost => plateau.
//   Dispatch +>10us => f32 gather too costly => restore NBF.
//   Keeps (R32): 4 blocks/CU, N-split, fused K-half-2 w/ |.|-modifier
//   cvt_pk comb2, pkbf epilogues, vectorized sW3 Phase F.

#define H 128

typedef __bf16 bf16x8 __attribute__((ext_vector_type(8)));
typedef float f32x4 __attribute__((ext_vector_type(4)));

__device__ __forceinline__ unsigned short f2bf(float f) {
    unsigned u = __builtin_bit_cast(unsigned, f);
    u += 0x7FFFu + ((u >> 16) & 1u);   // RNE
    return (unsigned short)(u >> 16);
}
__device__ __forceinline__ float bfhi(unsigned u) {
    return __builtin_bit_cast(float, u & 0xffff0000u);
}
__device__ __forceinline__ float bflo(unsigned u) {
    return __builtin_bit_cast(float, u << 16);
}
// Shared-extract diff+prod: abs folded into cvt_pk input modifiers.
__device__ __forceinline__ void comb2(unsigned ua, unsigned ub,
                                      unsigned& dd, unsigned& pp) {
    float a0 = bflo(ua), a1 = bfhi(ua);
    float b0 = bflo(ub), b1 = bfhi(ub);
    float d0 = a0 - b0, d1 = a1 - b1;
    float p0 = a0 * b0, p1 = a1 * b1;
    unsigned rd, rp;
    asm("v_cvt_pk_bf16_f32 %0, |%1|, |%2|" : "=v"(rd) : "v"(d0), "v"(d1));
    asm("v_cvt_pk_bf16_f32 %0, %1, %2" : "=v"(rp) : "v"(p0), "v"(p1));
    dd = rd; pp = rp;
}
// Pack two f32 to bf16 pair (RNE).
__device__ __forceinline__ unsigned pkbf(float v0, float v1) {
    unsigned r;
    asm("v_cvt_pk_bf16_f32 %0, %1, %2" : "=v"(r) : "v"(v0), "v"(v1));
    return r;
}

// Merged fragment-major packs of W1 [512][256] and W2 [256][128].
//   Blocks 0..511:   W1P[o], o = blockIdx*256+t; row = g_nt*16+(lane&15),
//                    k = ks*32+(lane>>4)*8+j  (chunk = o>>9 = g_nt*16+ks)
//   Blocks 512..639: W2P[o], o = (blockIdx-512)*256+t; same scheme, 8 ks.
__global__ void prep_w(const float* __restrict__ W1, const float* __restrict__ W2,
                       unsigned short* __restrict__ W1P, unsigned short* __restrict__ W2P) {
    if (blockIdx.x < 512) {
        int o = blockIdx.x * 256 + threadIdx.x;        // 131072 total
        int chunk = o >> 9;
        int g_nt = chunk >> 4;
        int ks = chunk & 15;
        int r = o & 511;
        int lane = r >> 3;
        int j = r & 7;
        int row = g_nt * 16 + (lane & 15);
        int k = ks * 32 + (lane >> 4) * 8 + j;
        W1P[o] = f2bf(W1[k * 256 + row]);
    } else {
        int o = (blockIdx.x - 512) * 256 + threadIdx.x; // 32768 total
        int chunk = o >> 9;
        int g_nt = chunk >> 3;
        int ks = chunk & 7;
        int r = o & 511;
        int lane = r >> 3;
        int j = r & 7;
        int row = g_nt * 16 + (lane & 15);
        int k = ks * 32 + (lane >> 4) * 8 + j;
        W2P[o] = f2bf(W2[k * 128 + row]);
    }
}

__launch_bounds__(256, 4)
__global__ void fused_mlp(const float* __restrict__ node,           // [N][128] f32
                          const int* __restrict__ src,
                          const int* __restrict__ dst,
                          const unsigned short* __restrict__ W1P,  // packed
                          const float* __restrict__ b1,
                          const unsigned short* __restrict__ W2P,  // packed
                          const float* __restrict__ b2,
                          const float* __restrict__ W3,            // [128][2] f32
                          const float* __restrict__ b3,
                          float* __restrict__ out,                 // [E][2] f32
                          int E) {
    // sH: [64][268] bf16. Region P (cols 0..127): hi (never overwritten
    //     during layer 1). Region Q (cols 136..263): hj.
    // Overlays: x1 [64][268] cols 0..255 (after barrier); x2 [64][140].
    __shared__ __align__(16) unsigned short sH[64 * 268];    // 34304 B
    __shared__ __align__(16) float sW3[256];                 // [c][128]

    const int t = threadIdx.x;
    const int e0 = blockIdx.x * 64;

    const int lane = t & 63;
    const int wv = t >> 6;
    const int quad = lane >> 4;
    const int lrow = lane & 15;
    const int nb = wv * 64;        // layer-1 N-slice
    const int nb2 = wv * 32;       // layer-2 N-slice

    // Weight stream bases (N-split: each wave streams ONLY its N-slices).
    const unsigned short* w1b = W1P + wv * 32768 + lane * 8;   // wv*4*16*512
    const unsigned short* w2b = W2P + wv * 8192 + lane * 8;    // wv*2*8*512

    // ---------------- Phase A: gather f32 hi/hj -> bf16 -> LDS ------------------
    // Direct f32 gather (prep_node eliminated); cvt_pk RNE == f2bf RNE, so
    // LDS contents are bit-identical to the old NBF path.
    {
        int r = t >> 2;            // edge row 0..63
        int q = t & 3;             // 32-col quarter (128 B f32)
        int e = e0 + r;
        int ec = e < E ? e : (E - 1);
        const float* hi = node + (long)src[ec] * H + q * 32;
        const float* hj = node + (long)dst[ec] * H + q * 32;
        unsigned short* rowp = sH + r * 268 + q * 32;
#pragma unroll
        for (int b = 0; b < 4; b++) {
            f32x4 a0 = *(const f32x4*)(hi + b * 8);
            f32x4 a1 = *(const f32x4*)(hi + b * 8 + 4);
            f32x4 c0 = *(const f32x4*)(hj + b * 8);
            f32x4 c1 = *(const f32x4*)(hj + b * 8 + 4);
            uint4 a, c;
            a.x = pkbf(a0[0], a0[1]); a.y = pkbf(a0[2], a0[3]);
            a.z = pkbf(a1[0], a1[1]); a.w = pkbf(a1[2], a1[3]);
            c.x = pkbf(c0[0], c0[1]); c.y = pkbf(c0[2], c0[3]);
            c.z = pkbf(c1[0], c1[1]); c.w = pkbf(c1[2], c1[3]);
            *(uint4*)(rowp + b * 8)       = a;
            *(uint4*)(rowp + 136 + b * 8) = c;
        }
        sW3[(t & 1) * 128 + (t >> 1)] = W3[t];   // [k][c] -> [c][k]
    }
    __syncthreads();               // hi/hj visible

    // ---------------- Phase B: layer 1 (M=64, N=256, K=512), barrier-free -------
    f32x4 acc[4][4];
#pragma unroll
    for (int mt = 0; mt < 4; mt++)
#pragma unroll
        for (int nt = 0; nt < 4; nt++)
            acc[mt][nt] = (f32x4){0.f, 0.f, 0.f, 0.f};

    int aoff[4];
#pragma unroll
    for (int mt = 0; mt < 4; mt++) aoff[mt] = (mt * 16 + lrow) * 268 + quad * 8;

    // K-half 1: k 0..255  (A = hi | hj, as stored)
#pragma unroll 1
    for (int ks = 0; ks < 8; ks++) {
        const int ao = (ks < 4) ? ks * 32 : 136 + (ks - 4) * 32;
        bf16x8 bv[4], av[4];
#pragma unroll
        for (int nt = 0; nt < 4; nt++) bv[nt] = *(const bf16x8*)(w1b + nt * 8192 + ks * 512);
#pragma unroll
        for (int mt = 0; mt < 4; mt++) av[mt] = *(const bf16x8*)(sH + aoff[mt] + ao);
#pragma unroll
        for (int mt = 0; mt < 4; mt++)
#pragma unroll
            for (int nt = 0; nt < 4; nt++)
                acc[mt][nt] = __builtin_amdgcn_mfma_f32_16x16x32_bf16(av[mt], bv[nt], acc[mt][nt], 0, 0, 0);
    }

    // K-half 2 (fused): per ks, build diff (k-slice ks+8) AND prod (ks+12)
    // A-fragments from ONE hu/ju read with shared extracts, then MFMA both.
#pragma unroll 1
    for (int ks = 0; ks < 4; ks++) {
        bf16x8 avd[4], avp[4];
#pragma unroll
        for (int mt = 0; mt < 4; mt++) {
            uint4 hu = *(const uint4*)(sH + aoff[mt] + ks * 32);
            uint4 ju = *(const uint4*)(sH + aoff[mt] + 136 + ks * 32);
            uint4 cd, cp;
            comb2(hu.x, ju.x, cd.x, cp.x);
            comb2(hu.y, ju.y, cd.y, cp.y);
            comb2(hu.z, ju.z, cd.z, cp.z);
            comb2(hu.w, ju.w, cd.w, cp.w);
            avd[mt] = __builtin_bit_cast(bf16x8, cd);
            avp[mt] = __builtin_bit_cast(bf16x8, cp);
        }
#pragma unroll
        for (int nt = 0; nt < 4; nt++) {
            bf16x8 bvd = *(const bf16x8*)(w1b + nt * 8192 + (ks + 8) * 512);
            bf16x8 bvp = *(const bf16x8*)(w1b + nt * 8192 + (ks + 12) * 512);
#pragma unroll
            for (int mt = 0; mt < 4; mt++) {
                acc[mt][nt] = __builtin_amdgcn_mfma_f32_16x16x32_bf16(avd[mt], bvd, acc[mt][nt], 0, 0, 0);
                acc[mt][nt] = __builtin_amdgcn_mfma_f32_16x16x32_bf16(avp[mt], bvp, acc[mt][nt], 0, 0, 0);
            }
        }
    }

    // Hoisted: biases (needed in Phases C/E).
    float b1v[4];
#pragma unroll
    for (int nt = 0; nt < 4; nt++) b1v[nt] = b1[nb + nt * 16 + lrow];
    float b2v[2];
#pragma unroll
    for (int nt = 0; nt < 2; nt++) b2v[nt] = b2[nb2 + nt * 16 + lrow];

    // ---------------- Phase C: relu+bias -> x1 bf16 (overlay sH) ----------------
    __syncthreads();               // all layer-1 reads of sH done
    unsigned short* sx1 = sH;      // [64][268], cols 0..255
#pragma unroll
    for (int mt = 0; mt < 4; mt++)
#pragma unroll
        for (int nt = 0; nt < 4; nt++) {
            float v0 = acc[mt][nt][0] + b1v[nt]; v0 = v0 > 0.f ? v0 : 0.f;
            float v1 = acc[mt][nt][1] + b1v[nt]; v1 = v1 > 0.f ? v1 : 0.f;
            float v2 = acc[mt][nt][2] + b1v[nt]; v2 = v2 > 0.f ? v2 : 0.f;
            float v3 = acc[mt][nt][3] + b1v[nt]; v3 = v3 > 0.f ? v3 : 0.f;
            unsigned r01 = pkbf(v0, v1);
            unsigned r23 = pkbf(v2, v3);
            unsigned short* base = sx1 + (mt * 16 + quad * 4) * 268 + nb + nt * 16 + lrow;
            base[0]   = (unsigned short)r01;         // row quad*4+0
            base[268] = (unsigned short)(r01 >> 16); // row quad*4+1
            base[536] = (unsigned short)r23;         // row quad*4+2
            base[804] = (unsigned short)(r23 >> 16); // row quad*4+3
        }
    __syncthreads();               // x1 complete

    // ---------------- Phase D: layer 2 (M=64, N=128, K=256) ----------------
    f32x4 acc2[4][2];
#pragma unroll
    for (int mt = 0; mt < 4; mt++)
#pragma unroll
        for (int nt = 0; nt < 2; nt++)
            acc2[mt][nt] = (f32x4){0.f, 0.f, 0.f, 0.f};

#pragma unroll 1
    for (int ks = 0; ks < 8; ks++) {
        bf16x8 bv2[2], av2[4];
#pragma unroll
        for (int nt = 0; nt < 2; nt++) bv2[nt] = *(const bf16x8*)(w2b + nt * 4096 + ks * 512);
#pragma unroll
        for (int mt = 0; mt < 4; mt++) av2[mt] = *(const bf16x8*)(sx1 + aoff[mt] + ks * 32);
#pragma unroll
        for (int mt = 0; mt < 4; mt++)
#pragma unroll
            for (int nt = 0; nt < 2; nt++)
                acc2[mt][nt] = __builtin_amdgcn_mfma_f32_16x16x32_bf16(av2[mt], bv2[nt], acc2[mt][nt], 0, 0, 0);
    }

    // ---------------- Phase E: relu+bias -> x2 bf16 (overlay) ----------------
    __syncthreads();               // all layer-2 reads of x1 done
    unsigned short* sx2 = sH;      // [64][140] (70 dw stride, gcd 2 -> free)
#pragma unroll
    for (int mt = 0; mt < 4; mt++)
#pragma unroll
        for (int nt = 0; nt < 2; nt++) {
            float v0 = acc2[mt][nt][0] + b2v[nt]; v0 = v0 > 0.f ? v0 : 0.f;
            float v1 = acc2[mt][nt][1] + b2v[nt]; v1 = v1 > 0.f ? v1 : 0.f;
            float v2 = acc2[mt][nt][2] + b2v[nt]; v2 = v2 > 0.f ? v2 : 0.f;
            float v3 = acc2[mt][nt][3] + b2v[nt]; v3 = v3 > 0.f ? v3 : 0.f;
            unsigned r01 = pkbf(v0, v1);
            unsigned r23 = pkbf(v2, v3);
            unsigned short* base = sx2 + (mt * 16 + quad * 4) * 140 + nb2 + nt * 16 + lrow;
            base[0]   = (unsigned short)r01;
            base[140] = (unsigned short)(r01 >> 16);
            base[280] = (unsigned short)r23;
            base[420] = (unsigned short)(r23 >> 16);
        }
    __syncthreads();

    // ---------------- Phase F: layer 3 (N=2), half-dots + shfl ----------------
    {
        int r = t >> 2;            // edge row 0..63
        int c = t & 1;             // class
        int h = (t >> 1) & 1;      // K-half
        const unsigned short* xr = sx2 + r * 140 + h * 64;
        const float* w3c = sW3 + c * 128 + h * 64;
        float s = 0.f;
#pragma unroll
        for (int j = 0; j < 8; j++) {
            uint4 v = *(const uint4*)(xr + j * 8);
            f32x4 w0 = *(const f32x4*)(w3c + j * 8);
            f32x4 w1 = *(const f32x4*)(w3c + j * 8 + 4);
            s += bflo(v.x) * w0[0] + bfhi(v.x) * w0[1]
               + bflo(v.y) * w0[2] + bfhi(v.y) * w0[3]
               + bflo(v.z) * w1[0] + bfhi(v.z) * w1[1]
               + bflo(v.w) * w1[2] + bfhi(v.w) * w1[3];
        }
        s += __shfl_xor(s, 2);     // combine K-halves
        int e = e0 + r;
        if (h == 0 && e < E) out[e * 2 + c] = s + b3[c];
    }
}

extern "C" void kernel_launch(void* const* d_in, const int* in_sizes, int n_in,
                              void* d_out, int out_size, void* d_ws, size_t ws_size,
                              hipStream_t stream) {
    const float* node = (const float*)d_in[0];
    const int* src    = (const int*)d_in[1];
    const int* dst    = (const int*)d_in[2];
    const float* W1   = (const float*)d_in[3];
    const float* b1   = (const float*)d_in[4];
    const float* W2   = (const float*)d_in[5];
    const float* b2   = (const float*)d_in[6];
    const float* W3   = (const float*)d_in[7];
    const float* b3   = (const float*)d_in[8];
    float* out = (float*)d_out;
    const int E = in_sizes[1];

    unsigned short* W1P = (unsigned short*)d_ws;       // packed W1, 256 KiB
    unsigned short* W2P = W1P + 512 * 256;             // packed W2, 64 KiB

    hipLaunchKernelGGL(prep_w, dim3(640), dim3(256), 0, stream, W1, W2, W1P, W2P);
    const int nblk = (E + 63) / 64;
    hipLaunchKernelGGL(fused_mlp, dim3(nblk), dim3(256), 0, stream,
                       node, src, dst, W1P, b1, W2P, b2, W3, b3, out, E);
}

// Round 22
// 333.593 us; speedup vs baseline: 1.1163x; 1.1163x over previous
//
#include <hip/hip_runtime.h>

// EntityLinker fused edge-MLP for MI355X (gfx950).
// Round 34: revert R33's f32 gather (pre-committed branch); keep launch merge.
//   R33 post-mortem: dropping prep_node REGRESSED (dispatch 287 -> 332,
//   FETCH 94 -> 227MB, WRITE 5x): the f32 gather's extra bytes + exposed
//   head latency cost 3x what the prep tail saved. The bf16 node cache
//   earns its 12.8MB roundtrip. Restore R32 interior verbatim (best
//   measured, 287.0us) and keep the tail trim by merging ALL prep into
//   ONE kernel (prep_all = node-cvt 6250 blks + w1-pack 512 + w2-pack
//   128, each path byte-identical to measured R32 code). Launches 4 -> 2.
//   Predict: dispatch 287 +- 2 (FETCH ~94MB, VGPR 60); bench 337 ->
//   ~327-334. Bench flat => tail is fixed harness cost => declare
//   plateau next round. Bench regression => revert to 3-launch R32.
//   Keeps (R32): 4 blocks/CU, N-split, bf16 node cache, fused K-half-2
//   w/ |.|-modifier cvt_pk comb2, pkbf epilogues, vectorized sW3.

#define H 128

typedef __bf16 bf16x8 __attribute__((ext_vector_type(8)));
typedef float f32x4 __attribute__((ext_vector_type(4)));

__device__ __forceinline__ unsigned short f2bf(float f) {
    unsigned u = __builtin_bit_cast(unsigned, f);
    u += 0x7FFFu + ((u >> 16) & 1u);   // RNE
    return (unsigned short)(u >> 16);
}
__device__ __forceinline__ float bfhi(unsigned u) {
    return __builtin_bit_cast(float, u & 0xffff0000u);
}
__device__ __forceinline__ float bflo(unsigned u) {
    return __builtin_bit_cast(float, u << 16);
}
// Shared-extract diff+prod: abs folded into cvt_pk input modifiers.
__device__ __forceinline__ void comb2(unsigned ua, unsigned ub,
                                      unsigned& dd, unsigned& pp) {
    float a0 = bflo(ua), a1 = bfhi(ua);
    float b0 = bflo(ub), b1 = bfhi(ub);
    float d0 = a0 - b0, d1 = a1 - b1;
    float p0 = a0 * b0, p1 = a1 * b1;
    unsigned rd, rp;
    asm("v_cvt_pk_bf16_f32 %0, |%1|, |%2|" : "=v"(rd) : "v"(d0), "v"(d1));
    asm("v_cvt_pk_bf16_f32 %0, %1, %2" : "=v"(rp) : "v"(p0), "v"(p1));
    dd = rd; pp = rp;
}
// Pack two f32 to bf16 pair (RNE), for epilogues.
__device__ __forceinline__ unsigned pkbf(float v0, float v1) {
    unsigned r;
    asm("v_cvt_pk_bf16_f32 %0, %1, %2" : "=v"(r) : "v"(v0), "v"(v1));
    return r;
}

// Merged prep: node f32->bf16 cache (blocks 0..nodeBlks-1), fragment-major
// W1 pack (next 512 blocks), W2 pack (next 128). Each path byte-identical
// to the measured R32 kernels.
__global__ void prep_all(const float* __restrict__ node, unsigned short* __restrict__ nbf,
                         int nodeBlks,
                         const float* __restrict__ W1, const float* __restrict__ W2,
                         unsigned short* __restrict__ W1P, unsigned short* __restrict__ W2P) {
    int bx = blockIdx.x;
    if (bx < nodeBlks) {
        int idx = bx * 256 + threadIdx.x;              // N*H/4 threads, 4 elems each
        const f32x4* p = (const f32x4*)(node) + idx;
        f32x4 v = *p;
        ushort4 w;
        w.x = f2bf(v.x); w.y = f2bf(v.y); w.z = f2bf(v.z); w.w = f2bf(v.w);
        *(ushort4*)(nbf + idx * 4) = w;
    } else if (bx < nodeBlks + 512) {
        int o = (bx - nodeBlks) * 256 + threadIdx.x;   // 131072 total
        int chunk = o >> 9;
        int g_nt = chunk >> 4;
        int ks = chunk & 15;
        int r = o & 511;
        int lane = r >> 3;
        int j = r & 7;
        int row = g_nt * 16 + (lane & 15);
        int k = ks * 32 + (lane >> 4) * 8 + j;
        W1P[o] = f2bf(W1[k * 256 + row]);
    } else {
        int o = (bx - nodeBlks - 512) * 256 + threadIdx.x; // 32768 total
        int chunk = o >> 9;
        int g_nt = chunk >> 3;
        int ks = chunk & 7;
        int r = o & 511;
        int lane = r >> 3;
        int j = r & 7;
        int row = g_nt * 16 + (lane & 15);
        int k = ks * 32 + (lane >> 4) * 8 + j;
        W2P[o] = f2bf(W2[k * 128 + row]);
    }
}

__launch_bounds__(256, 4)
__global__ void fused_mlp(const unsigned short* __restrict__ nbf,   // [N][128] bf16
                          const int* __restrict__ src,
                          const int* __restrict__ dst,
                          const unsigned short* __restrict__ W1P,  // packed
                          const float* __restrict__ b1,
                          const unsigned short* __restrict__ W2P,  // packed
                          const float* __restrict__ b2,
                          const float* __restrict__ W3,            // [128][2] f32
                          const float* __restrict__ b3,
                          float* __restrict__ out,                 // [E][2] f32
                          int E) {
    // sH: [64][268] bf16. Region P (cols 0..127): hi (never overwritten
    //     during layer 1). Region Q (cols 136..263): hj.
    // Overlays: x1 [64][268] cols 0..255 (after barrier); x2 [64][140].
    __shared__ __align__(16) unsigned short sH[64 * 268];    // 34304 B
    __shared__ __align__(16) float sW3[256];                 // [c][128]

    const int t = threadIdx.x;
    const int e0 = blockIdx.x * 64;

    const int lane = t & 63;
    const int wv = t >> 6;
    const int quad = lane >> 4;
    const int lrow = lane & 15;
    const int nb = wv * 64;        // layer-1 N-slice
    const int nb2 = wv * 32;       // layer-2 N-slice

    // Weight stream bases (N-split: each wave streams ONLY its N-slices).
    const unsigned short* w1b = W1P + wv * 32768 + lane * 8;   // wv*4*16*512
    const unsigned short* w2b = W2P + wv * 8192 + lane * 8;    // wv*2*8*512

    // ---------------- Phase A: gather hi/hj (bf16) -> LDS, line-granular --------
    {
        int r = t >> 2;            // edge row 0..63
        int q = t & 3;             // 32-col quarter (64 B = one cache line)
        int e = e0 + r;
        int ec = e < E ? e : (E - 1);
        const unsigned short* hi = nbf + (long)src[ec] * H + q * 32;
        const unsigned short* hj = nbf + (long)dst[ec] * H + q * 32;
        unsigned short* rowp = sH + r * 268 + q * 32;
#pragma unroll
        for (int b = 0; b < 4; b++) {
            uint4 a = *(const uint4*)(hi + b * 8);
            uint4 c = *(const uint4*)(hj + b * 8);
            *(uint4*)(rowp + b * 8)       = a;
            *(uint4*)(rowp + 136 + b * 8) = c;
        }
        sW3[(t & 1) * 128 + (t >> 1)] = W3[t];   // [k][c] -> [c][k]
    }
    __syncthreads();               // hi/hj visible

    // ---------------- Phase B: layer 1 (M=64, N=256, K=512), barrier-free -------
    f32x4 acc[4][4];
#pragma unroll
    for (int mt = 0; mt < 4; mt++)
#pragma unroll
        for (int nt = 0; nt < 4; nt++)
            acc[mt][nt] = (f32x4){0.f, 0.f, 0.f, 0.f};

    int aoff[4];
#pragma unroll
    for (int mt = 0; mt < 4; mt++) aoff[mt] = (mt * 16 + lrow) * 268 + quad * 8;

    // K-half 1: k 0..255  (A = hi | hj, as stored)
#pragma unroll 1
    for (int ks = 0; ks < 8; ks++) {
        const int ao = (ks < 4) ? ks * 32 : 136 + (ks - 4) * 32;
        bf16x8 bv[4], av[4];
#pragma unroll
        for (int nt = 0; nt < 4; nt++) bv[nt] = *(const bf16x8*)(w1b + nt * 8192 + ks * 512);
#pragma unroll
        for (int mt = 0; mt < 4; mt++) av[mt] = *(const bf16x8*)(sH + aoff[mt] + ao);
#pragma unroll
        for (int mt = 0; mt < 4; mt++)
#pragma unroll
            for (int nt = 0; nt < 4; nt++)
                acc[mt][nt] = __builtin_amdgcn_mfma_f32_16x16x32_bf16(av[mt], bv[nt], acc[mt][nt], 0, 0, 0);
    }

    // K-half 2 (fused): per ks, build diff (k-slice ks+8) AND prod (ks+12)
    // A-fragments from ONE hu/ju read with shared extracts, then MFMA both.
#pragma unroll 1
    for (int ks = 0; ks < 4; ks++) {
        bf16x8 avd[4], avp[4];
#pragma unroll
        for (int mt = 0; mt < 4; mt++) {
            uint4 hu = *(const uint4*)(sH + aoff[mt] + ks * 32);
            uint4 ju = *(const uint4*)(sH + aoff[mt] + 136 + ks * 32);
            uint4 cd, cp;
            comb2(hu.x, ju.x, cd.x, cp.x);
            comb2(hu.y, ju.y, cd.y, cp.y);
            comb2(hu.z, ju.z, cd.z, cp.z);
            comb2(hu.w, ju.w, cd.w, cp.w);
            avd[mt] = __builtin_bit_cast(bf16x8, cd);
            avp[mt] = __builtin_bit_cast(bf16x8, cp);
        }
#pragma unroll
        for (int nt = 0; nt < 4; nt++) {
            bf16x8 bvd = *(const bf16x8*)(w1b + nt * 8192 + (ks + 8) * 512);
            bf16x8 bvp = *(const bf16x8*)(w1b + nt * 8192 + (ks + 12) * 512);
#pragma unroll
            for (int mt = 0; mt < 4; mt++) {
                acc[mt][nt] = __builtin_amdgcn_mfma_f32_16x16x32_bf16(avd[mt], bvd, acc[mt][nt], 0, 0, 0);
                acc[mt][nt] = __builtin_amdgcn_mfma_f32_16x16x32_bf16(avp[mt], bvp, acc[mt][nt], 0, 0, 0);
            }
        }
    }

    // Hoisted: biases (needed in Phases C/E).
    float b1v[4];
#pragma unroll
    for (int nt = 0; nt < 4; nt++) b1v[nt] = b1[nb + nt * 16 + lrow];
    float b2v[2];
#pragma unroll
    for (int nt = 0; nt < 2; nt++) b2v[nt] = b2[nb2 + nt * 16 + lrow];

    // ---------------- Phase C: relu+bias -> x1 bf16 (overlay sH) ----------------
    __syncthreads();               // all layer-1 reads of sH done
    unsigned short* sx1 = sH;      // [64][268], cols 0..255
#pragma unroll
    for (int mt = 0; mt < 4; mt++)
#pragma unroll
        for (int nt = 0; nt < 4; nt++) {
            float v0 = acc[mt][nt][0] + b1v[nt]; v0 = v0 > 0.f ? v0 : 0.f;
            float v1 = acc[mt][nt][1] + b1v[nt]; v1 = v1 > 0.f ? v1 : 0.f;
            float v2 = acc[mt][nt][2] + b1v[nt]; v2 = v2 > 0.f ? v2 : 0.f;
            float v3 = acc[mt][nt][3] + b1v[nt]; v3 = v3 > 0.f ? v3 : 0.f;
            unsigned r01 = pkbf(v0, v1);
            unsigned r23 = pkbf(v2, v3);
            unsigned short* base = sx1 + (mt * 16 + quad * 4) * 268 + nb + nt * 16 + lrow;
            base[0]   = (unsigned short)r01;         // row quad*4+0
            base[268] = (unsigned short)(r01 >> 16); // row quad*4+1
            base[536] = (unsigned short)r23;         // row quad*4+2
            base[804] = (unsigned short)(r23 >> 16); // row quad*4+3
        }
    __syncthreads();               // x1 complete

    // ---------------- Phase D: layer 2 (M=64, N=128, K=256) ----------------
    f32x4 acc2[4][2];
#pragma unroll
    for (int mt = 0; mt < 4; mt++)
#pragma unroll
        for (int nt = 0; nt < 2; nt++)
            acc2[mt][nt] = (f32x4){0.f, 0.f, 0.f, 0.f};

#pragma unroll 1
    for (int ks = 0; ks < 8; ks++) {
        bf16x8 bv2[2], av2[4];
#pragma unroll
        for (int nt = 0; nt < 2; nt++) bv2[nt] = *(const bf16x8*)(w2b + nt * 4096 + ks * 512);
#pragma unroll
        for (int mt = 0; mt < 4; mt++) av2[mt] = *(const bf16x8*)(sx1 + aoff[mt] + ks * 32);
#pragma unroll
        for (int mt = 0; mt < 4; mt++)
#pragma unroll
            for (int nt = 0; nt < 2; nt++)
                acc2[mt][nt] = __builtin_amdgcn_mfma_f32_16x16x32_bf16(av2[mt], bv2[nt], acc2[mt][nt], 0, 0, 0);
    }

    // ---------------- Phase E: relu+bias -> x2 bf16 (overlay) ----------------
    __syncthreads();               // all layer-2 reads of x1 done
    unsigned short* sx2 = sH;      // [64][140] (70 dw stride, gcd 2 -> free)
#pragma unroll
    for (int mt = 0; mt < 4; mt++)
#pragma unroll
        for (int nt = 0; nt < 2; nt++) {
            float v0 = acc2[mt][nt][0] + b2v[nt]; v0 = v0 > 0.f ? v0 : 0.f;
            float v1 = acc2[mt][nt][1] + b2v[nt]; v1 = v1 > 0.f ? v1 : 0.f;
            float v2 = acc2[mt][nt][2] + b2v[nt]; v2 = v2 > 0.f ? v2 : 0.f;
            float v3 = acc2[mt][nt][3] + b2v[nt]; v3 = v3 > 0.f ? v3 : 0.f;
            unsigned r01 = pkbf(v0, v1);
            unsigned r23 = pkbf(v2, v3);
            unsigned short* base = sx2 + (mt * 16 + quad * 4) * 140 + nb2 + nt * 16 + lrow;
            base[0]   = (unsigned short)r01;
            base[140] = (unsigned short)(r01 >> 16);
            base[280] = (unsigned short)r23;
            base[420] = (unsigned short)(r23 >> 16);
        }
    __syncthreads();

    // ---------------- Phase F: layer 3 (N=2), half-dots + shfl ----------------
    {
        int r = t >> 2;            // edge row 0..63
        int c = t & 1;             // class
        int h = (t >> 1) & 1;      // K-half
        const unsigned short* xr = sx2 + r * 140 + h * 64;
        const float* w3c = sW3 + c * 128 + h * 64;
        float s = 0.f;
#pragma unroll
        for (int j = 0; j < 8; j++) {
            uint4 v = *(const uint4*)(xr + j * 8);
            f32x4 w0 = *(const f32x4*)(w3c + j * 8);
            f32x4 w1 = *(const f32x4*)(w3c + j * 8 + 4);
            s += bflo(v.x) * w0[0] + bfhi(v.x) * w0[1]
               + bflo(v.y) * w0[2] + bfhi(v.y) * w0[3]
               + bflo(v.z) * w1[0] + bfhi(v.z) * w1[1]
               + bflo(v.w) * w1[2] + bfhi(v.w) * w1[3];
        }
        s += __shfl_xor(s, 2);     // combine K-halves
        int e = e0 + r;
        if (h == 0 && e < E) out[e * 2 + c] = s + b3[c];
    }
}

extern "C" void kernel_launch(void* const* d_in, const int* in_sizes, int n_in,
                              void* d_out, int out_size, void* d_ws, size_t ws_size,
                              hipStream_t stream) {
    const float* node = (const float*)d_in[0];
    const int* src    = (const int*)d_in[1];
    const int* dst    = (const int*)d_in[2];
    const float* W1   = (const float*)d_in[3];
    const float* b1   = (const float*)d_in[4];
    const float* W2   = (const float*)d_in[5];
    const float* b2   = (const float*)d_in[6];
    const float* W3   = (const float*)d_in[7];
    const float* b3   = (const float*)d_in[8];
    float* out = (float*)d_out;
    const int NN = in_sizes[0] / H;                    // 50000 nodes
    const int E = in_sizes[1];

    unsigned short* W1P = (unsigned short*)d_ws;       // packed W1, 256 KiB
    unsigned short* W2P = W1P + 512 * 256;             // packed W2, 64 KiB
    unsigned short* NBF = W2P + 256 * 128;             // [N][128] bf16, 12.8 MB

    const int nodeBlks = (NN * H / 4 + 255) / 256;     // 6250
    hipLaunchKernelGGL(prep_all, dim3(nodeBlks + 640), dim3(256), 0, stream,
                       node, NBF, nodeBlks, W1, W2, W1P, W2P);
    const int nblk = (E + 63) / 64;
    hipLaunchKernelGGL(fused_mlp, dim3(nblk), dim3(256), 0, stream,
                       NBF, src, dst, W1P, b1, W2P, b2, W3, b3, out, E);
}